// Round 8
// baseline (284.373 us; speedup 1.0000x reference)
//
#include <hip/hip_runtime.h>
#include <math.h>

#define BB 4
#define CC 256
#define DD 32
#define NN 4096

typedef __attribute__((ext_vector_type(8))) short short8;
typedef __attribute__((ext_vector_type(4))) float floatx4;
typedef __attribute__((ext_vector_type(4))) int intx4;

#define SCALEF (0.17677669529663687f * 1.4426950408889634f)  // 1/sqrt(32)*log2(e)

// float -> bf16 round-to-nearest-even
__device__ __forceinline__ ushort f2bf(float f) {
    unsigned int u = __builtin_bit_cast(unsigned int, f);
    u += 0x7FFFu + ((u >> 16) & 1u);
    return (ushort)(u >> 16);
}
// pack two floats' bf16 truncations into one dword with a single v_perm_b32
__device__ __forceinline__ int pk_trunc(float a, float b) {
    return (int)__builtin_amdgcn_perm(__builtin_bit_cast(unsigned, b),
                                      __builtin_bit_cast(unsigned, a),
                                      0x07060302u);
}
__device__ __forceinline__ float fast_exp2(float x) {
#if __has_builtin(__builtin_amdgcn_exp2f)
    return __builtin_amdgcn_exp2f(x);
#else
    return exp2f(x);
#endif
}

// ---------------------------------------------------------------------------
// Kernel 0: x (B,C,N) fp32 -> xT (B,N,C) bf16 via LDS transpose.
// Coalesced float4 reads along N; 32B-contiguous bf16 writes along C.
// ---------------------------------------------------------------------------
__global__ __launch_bounds__(256) void x_transpose(
    const float* __restrict__ x, ushort* __restrict__ xT)
{
    __shared__ float T[64][65];
    const int t = threadIdx.x;
    const int b = blockIdx.z;
    const int c0 = blockIdx.y * 64;
    const int n0 = blockIdx.x * 64;

    #pragma unroll
    for (int r = 0; r < 4; ++r) {
        const int c = (t >> 4) + r * 16;
        const int n = (t & 15) * 4;
        float4 v = *(const float4*)(x + ((size_t)b * CC + c0 + c) * NN + n0 + n);
        T[c][n + 0] = v.x; T[c][n + 1] = v.y; T[c][n + 2] = v.z; T[c][n + 3] = v.w;
    }
    __syncthreads();

    const int n = t >> 2;
    const int cb = (t & 3) * 16;
    ushort* dst = xT + ((size_t)b * NN + n0 + n) * CC + c0 + cb;
    #pragma unroll
    for (int g = 0; g < 4; ++g) {
        ushort4 h;
        h.x = f2bf(T[cb + g * 4 + 0][n]);
        h.y = f2bf(T[cb + g * 4 + 1][n]);
        h.z = f2bf(T[cb + g * 4 + 2][n]);
        h.w = f2bf(T[cb + g * 4 + 3][n]);
        *(ushort4*)(dst + g * 4) = h;
    }
}

// ---------------------------------------------------------------------------
// Kernel 1: MFMA QKV projection, mirror of proj_mfma (both operands
// K-contiguous).  A-frags: fp32 W rows + v_perm pack (L2-hot).  B-frags:
// straight short8 loads from xT (B,N,C).  Wave tile = 64o x 32n; 2560 waves.
// q pre-scaled by 1/sqrt(32)*log2(e).  Outputs qb,kb (B,N,32), vb (B,C,N).
// ---------------------------------------------------------------------------
__global__ __launch_bounds__(256) void qkv_mfma(
    const ushort* __restrict__ xT,
    const float* __restrict__ Wq, const float* __restrict__ bq,
    const float* __restrict__ Wk, const float* __restrict__ bk,
    const float* __restrict__ Wv, const float* __restrict__ bv,
    ushort* __restrict__ qb, ushort* __restrict__ kb, ushort* __restrict__ vb)
{
    const int t = threadIdx.x;
    const int wave = t >> 6;
    const int lane = t & 63;
    const int l15 = lane & 15, qd = lane >> 4;
    const int b = blockIdx.z, m0 = blockIdx.y * 64;
    const int n0 = blockIdx.x * 128 + wave * 32;
    const bool isqk = (m0 == 0);

    const float* wr[4];
    if (isqk) {
        wr[0] = Wq + (size_t)l15 * CC;
        wr[1] = Wq + (size_t)(16 + l15) * CC;
        wr[2] = Wk + (size_t)l15 * CC;
        wr[3] = Wk + (size_t)(16 + l15) * CC;
    } else {
        #pragma unroll
        for (int f = 0; f < 4; ++f) wr[f] = Wv + (size_t)(m0 - 64 + f * 16 + l15) * CC;
    }

    const ushort* arow = xT + ((size_t)b * NN + n0 + l15) * CC + qd * 8;

    floatx4 z = {0.f, 0.f, 0.f, 0.f};
    floatx4 acc[4][2];
    #pragma unroll
    for (int i = 0; i < 4; ++i) { acc[i][0] = z; acc[i][1] = z; }

    #pragma unroll
    for (int k0 = 0; k0 < CC; k0 += 32) {
        short8 af[4], bf[2];
        #pragma unroll
        for (int f = 0; f < 4; ++f) {
            const float* p = wr[f] + k0 + qd * 8;
            float w[8];
            #pragma unroll
            for (int j = 0; j < 8; ++j) w[j] = p[j];
            if (isqk && f < 2) {
                #pragma unroll
                for (int j = 0; j < 8; ++j) w[j] *= SCALEF;
            }
            intx4 d;
            d[0] = pk_trunc(w[0], w[1]); d[1] = pk_trunc(w[2], w[3]);
            d[2] = pk_trunc(w[4], w[5]); d[3] = pk_trunc(w[6], w[7]);
            af[f] = __builtin_bit_cast(short8, d);
        }
        #pragma unroll
        for (int f = 0; f < 2; ++f)
            bf[f] = *(const short8*)(arow + (size_t)f * 16 * CC + k0);
        #pragma unroll
        for (int fm = 0; fm < 4; ++fm)
            #pragma unroll
            for (int fn = 0; fn < 2; ++fn)
                acc[fm][fn] = __builtin_amdgcn_mfma_f32_16x16x32_bf16(af[fm], bf[fn], acc[fm][fn], 0, 0, 0);
    }

    #pragma unroll
    for (int fm = 0; fm < 4; ++fm) {
        #pragma unroll
        for (int r = 0; r < 4; ++r) {
            int o = m0 + fm * 16 + qd * 4 + r;
            if (isqk) {
                if (fm < 2) {
                    float bo = bq[o] * SCALEF;
                    #pragma unroll
                    for (int fn = 0; fn < 2; ++fn)
                        qb[((size_t)b * NN + n0 + fn * 16 + l15) * DD + o] = f2bf(acc[fm][fn][r] + bo);
                } else {
                    float bo = bk[o - 32];
                    #pragma unroll
                    for (int fn = 0; fn < 2; ++fn)
                        kb[((size_t)b * NN + n0 + fn * 16 + l15) * DD + (o - 32)] = f2bf(acc[fm][fn][r] + bo);
                }
            } else {
                float bo = bv[o - 64];
                #pragma unroll
                for (int fn = 0; fn < 2; ++fn)
                    vb[((size_t)b * CC + (o - 64)) * NN + n0 + fn * 16 + l15] = f2bf(acc[fm][fn][r] + bo);
            }
        }
    }
}

// ---------------------------------------------------------------------------
// Kernel 2: MFMA flash attention with shared P (R7 structure, R8 schedule).
// Block = 4 waves = one 32-q tile x all 256 ch; wave w owns key-quarter w's
// S/exp/pack/transpose and publishes B-operand pt frags to double-buffered
// LDS P (1 barrier/tile).  R8 fix: ALL 16 V-frag loads are issued in one
// group immediately after the barrier (before P ds_reads/MFMAs), and the
// K(t+1) prefetch is issued after the barrier too — no load is ever drained
// by a barrier before its use, so per-tile exposed latency ~1 L2 trip.
// ---------------------------------------------------------------------------
__global__ __launch_bounds__(256) void attn_mfma(
    const ushort* __restrict__ qb, const ushort* __restrict__ kb,
    const ushort* __restrict__ vb, ushort* __restrict__ aoT)
{
    __shared__ short8 Pb[2][4][2][64];   // [buf][kc][f][lane] = 16 KB
    __shared__ float lredN[4][32];       // [wave][q]

    const int t = threadIdx.x;
    const int w = t >> 6;                // wave id = key-quarter owner & ch-group
    const int lane = t & 63;
    const int l15 = lane & 15, qd = lane >> 4;
    const int slot = blockIdx.x;         // ~XCD id (round-robin heuristic)
    const int b = slot >> 1;
    const int q0 = ((slot & 1) * 64 + blockIdx.y) * 32;
    const int c0 = w * 64;

    short8 qf[2];
    #pragma unroll
    for (int f = 0; f < 2; ++f)
        qf[f] = *(const short8*)(qb + ((size_t)b * NN + q0 + f * 16 + l15) * DD + qd * 8);

    const ushort* krow = kb + ((size_t)b * NN + w * 32 + l15) * DD + qd * 8;
    const ushort* vrow[4];
    #pragma unroll
    for (int ct = 0; ct < 4; ++ct)
        vrow[ct] = vb + ((size_t)b * CC + c0 + ct * 16 + l15) * (size_t)NN + qd * 8;

    const short8 ones = {0x3F80, 0x3F80, 0x3F80, 0x3F80, 0x3F80, 0x3F80, 0x3F80, 0x3F80};

    floatx4 z = {0.f, 0.f, 0.f, 0.f};
    floatx4 acc[2][4];   // [qfrag][chfrag]
    floatx4 accl[2];
    #pragma unroll
    for (int f = 0; f < 2; ++f) {
        accl[f] = z;
        #pragma unroll
        for (int c = 0; c < 4; ++c) acc[f][c] = z;
    }

    const int base  = (qd & 1) * 32 + l15;   // proven transpose lane mapping
    const int base2 = base + 16;
    const bool hi = (lane >= 32);

    // preload first K quarter
    short8 kf0 = *(const short8*)(krow);
    short8 kf1 = *(const short8*)(krow + 16 * DD);

    int buf = 0;
    for (int tile = 0; tile < 32; ++tile) {
        // S phase: this wave's 32-key quarter x 32 q
        floatx4 s0a = __builtin_amdgcn_mfma_f32_16x16x32_bf16(kf0, qf[0], z, 0, 0, 0);
        floatx4 s1a = __builtin_amdgcn_mfma_f32_16x16x32_bf16(kf1, qf[0], z, 0, 0, 0);
        floatx4 s0b = __builtin_amdgcn_mfma_f32_16x16x32_bf16(kf0, qf[1], z, 0, 0, 0);
        floatx4 s1b = __builtin_amdgcn_mfma_f32_16x16x32_bf16(kf1, qf[1], z, 0, 0, 0);

        #pragma unroll
        for (int f = 0; f < 2; ++f) {
            floatx4 s0 = f ? s0b : s0a;
            floatx4 s1 = f ? s1b : s1a;
            float e00 = fast_exp2(s0[0]), e01 = fast_exp2(s0[1]);
            float e02 = fast_exp2(s0[2]), e03 = fast_exp2(s0[3]);
            float e10 = fast_exp2(s1[0]), e11 = fast_exp2(s1[1]);
            float e12 = fast_exp2(s1[2]), e13 = fast_exp2(s1[3]);

            int A0 = pk_trunc(e00, e01);
            int A1 = pk_trunc(e02, e03);
            int B0 = pk_trunc(e10, e11);
            int B1 = pk_trunc(e12, e13);

            int w0a = __shfl(A0, base);  int w0b = __shfl(B0, base);
            int w1a = __shfl(A1, base);  int w1b = __shfl(B1, base);
            int w2a = __shfl(A0, base2); int w2b = __shfl(B0, base2);
            int w3a = __shfl(A1, base2); int w3b = __shfl(B1, base2);

            intx4 ptd;
            ptd[0] = hi ? w0b : w0a;
            ptd[1] = hi ? w1b : w1a;
            ptd[2] = hi ? w2b : w2a;
            ptd[3] = hi ? w3b : w3a;
            short8 pt = __builtin_bit_cast(short8, ptd);

            accl[f] = __builtin_amdgcn_mfma_f32_16x16x32_bf16(ones, pt, accl[f], 0, 0, 0);
            Pb[buf][w][f][lane] = pt;
        }

        __syncthreads();   // P published; prev buf's readers are 2 tiles back

        // issue ALL of this tile's V loads (consumed below) and the next
        // tile's K loads (consumed next iteration) — after the barrier, so
        // nothing gets vmcnt(0)-drained before use.
        short8 vf[16];
        #pragma unroll
        for (int kc = 0; kc < 4; ++kc)
            #pragma unroll
            for (int ct = 0; ct < 4; ++ct)
                vf[kc * 4 + ct] = *(const short8*)(vrow[ct] + kc * 32);
        krow += 128 * DD;     // last iter reads in-bounds ws; discarded
        kf0 = *(const short8*)(krow);
        kf1 = *(const short8*)(krow + 16 * DD);

        // PV phase: all 128 keys for this wave's 64 channels
        #pragma unroll
        for (int kc = 0; kc < 4; ++kc) {
            short8 pta = Pb[buf][kc][0][lane];
            short8 ptb = Pb[buf][kc][1][lane];
            #pragma unroll
            for (int ct = 0; ct < 4; ++ct) {
                acc[0][ct] = __builtin_amdgcn_mfma_f32_16x16x32_bf16(vf[kc * 4 + ct], pta, acc[0][ct], 0, 0, 0);
                acc[1][ct] = __builtin_amdgcn_mfma_f32_16x16x32_bf16(vf[kc * 4 + ct], ptb, acc[1][ct], 0, 0, 0);
            }
        }
        #pragma unroll
        for (int ct = 0; ct < 4; ++ct) vrow[ct] += 128;
        buf ^= 1;
    }

    // l reduction across the 4 key-quarter owners
    if (qd == 0) {
        lredN[w][l15]      = accl[0][0];
        lredN[w][16 + l15] = accl[1][0];
    }
    __syncthreads();
    #pragma unroll
    for (int f = 0; f < 2; ++f) {
        const float l = lredN[0][f * 16 + l15] + lredN[1][f * 16 + l15]
                      + lredN[2][f * 16 + l15] + lredN[3][f * 16 + l15];
        const float inv = 1.0f / l;
        ushort* dst = aoT + ((size_t)b * NN + q0 + f * 16 + l15) * CC + c0 + qd * 4;
        #pragma unroll
        for (int ct = 0; ct < 4; ++ct) {
            ushort4 h;
            h.x = f2bf(acc[f][ct][0] * inv);
            h.y = f2bf(acc[f][ct][1] * inv);
            h.z = f2bf(acc[f][ct][2] * inv);
            h.w = f2bf(acc[f][ct][3] * inv);
            *(ushort4*)(dst + ct * 16) = h;
        }
    }
}

// ---------------------------------------------------------------------------
// Kernel 3: MFMA output projection + residual.  Wave tile = 64m x 32n ->
// 512 blocks (2/CU).  A-frags cast from fp32 Wp in-register; B-frags
// straight short8 loads from bf16 aoT (B,N,C).  out = x + gamma*(Wp@ao+bp).
// ---------------------------------------------------------------------------
__global__ __launch_bounds__(256) void proj_mfma(
    const ushort* __restrict__ aoT, const float* __restrict__ Wp,
    const float* __restrict__ bp, const float* __restrict__ x,
    const float* __restrict__ gamma, float* __restrict__ out)
{
    const int t = threadIdx.x;
    const int wave = t >> 6;
    const int lane = t & 63;
    const int l15 = lane & 15;
    const int qd = lane >> 4;
    const int b = blockIdx.z;
    const int m0 = blockIdx.y * 64;
    const int n0 = blockIdx.x * 128 + wave * 32;

    floatx4 z = {0.f, 0.f, 0.f, 0.f};
    floatx4 acc[4][2];   // [fm][fn]
    #pragma unroll
    for (int i = 0; i < 4; ++i) { acc[i][0] = z; acc[i][1] = z; }

    const ushort* arow = aoT + ((size_t)b * NN + n0 + l15) * CC + qd * 8;
    const float* wrow = Wp + (size_t)(m0 + l15) * CC + qd * 8;

    #pragma unroll
    for (int k0 = 0; k0 < CC; k0 += 32) {
        short8 af[4], bf[2];
        #pragma unroll
        for (int f = 0; f < 4; ++f) {
            const float* p = wrow + (size_t)f * 16 * CC + k0;
            intx4 d;
            d[0] = pk_trunc(p[0], p[1]); d[1] = pk_trunc(p[2], p[3]);
            d[2] = pk_trunc(p[4], p[5]); d[3] = pk_trunc(p[6], p[7]);
            af[f] = __builtin_bit_cast(short8, d);
        }
        #pragma unroll
        for (int f = 0; f < 2; ++f)
            bf[f] = *(const short8*)(arow + (size_t)f * 16 * CC + k0);
        #pragma unroll
        for (int fm = 0; fm < 4; ++fm)
            #pragma unroll
            for (int fn = 0; fn < 2; ++fn)
                acc[fm][fn] = __builtin_amdgcn_mfma_f32_16x16x32_bf16(af[fm], bf[fn], acc[fm][fn], 0, 0, 0);
    }

    const float g = gamma[0];
    #pragma unroll
    for (int fm = 0; fm < 4; ++fm) {
        #pragma unroll
        for (int r = 0; r < 4; ++r) {
            int m = m0 + fm * 16 + qd * 4 + r;
            float bpv = bp[m];
            #pragma unroll
            for (int fn = 0; fn < 2; ++fn) {
                size_t addr = ((size_t)b * CC + m) * NN + n0 + fn * 16 + l15;
                out[addr] = fmaf(g, acc[fm][fn][r] + bpv, x[addr]);
            }
        }
    }
}

extern "C" void kernel_launch(void* const* d_in, const int* in_sizes, int n_in,
                              void* d_out, int out_size, void* d_ws, size_t ws_size,
                              hipStream_t stream)
{
    const float* x     = (const float*)d_in[0];
    const float* Wq    = (const float*)d_in[1];
    const float* bq    = (const float*)d_in[2];
    const float* Wk    = (const float*)d_in[3];
    const float* bk    = (const float*)d_in[4];
    const float* Wv    = (const float*)d_in[5];
    const float* bv    = (const float*)d_in[6];
    const float* Wp    = (const float*)d_in[7];
    const float* bp    = (const float*)d_in[8];
    const float* gamma = (const float*)d_in[9];
    float* out = (float*)d_out;

    ushort* qbw = (ushort*)d_ws;                        // B*N*32  bf16 = 1 MB
    ushort* kbw = qbw + (size_t)BB * NN * DD;           // B*N*32  bf16 = 1 MB
    ushort* vbw = kbw + (size_t)BB * NN * DD;           // B*C*N   bf16 = 8 MB
    ushort* aoT = vbw + (size_t)BB * CC * NN;           // B*N*C   bf16 = 8 MB
    ushort* xT  = aoT + (size_t)BB * NN * CC;           // B*N*C   bf16 = 8 MB

    x_transpose<<<dim3(NN / 64, CC / 64, BB), 256, 0, stream>>>(x, xT);
    qkv_mfma<<<dim3(NN / 128, 5, BB), 256, 0, stream>>>(xT, Wq, bq, Wk, bk, Wv, bv, qbw, kbw, vbw);
    attn_mfma<<<dim3(8, 64), 256, 0, stream>>>(qbw, kbw, vbw, aoT);
    proj_mfma<<<dim3(NN / 128, CC / 64, BB), 256, 0, stream>>>(aoT, Wp, bp, x, gamma, out);
}

// Round 9
// 233.536 us; speedup vs baseline: 1.2177x; 1.2177x over previous
//
#include <hip/hip_runtime.h>
#include <math.h>

#define BB 4
#define CC 256
#define DD 32
#define NN 4096

typedef __attribute__((ext_vector_type(8))) short short8;
typedef __attribute__((ext_vector_type(4))) float floatx4;
typedef __attribute__((ext_vector_type(4))) int intx4;

#define SCALEF (0.17677669529663687f * 1.4426950408889634f)  // 1/sqrt(32)*log2(e)

// float -> bf16 round-to-nearest-even
__device__ __forceinline__ ushort f2bf(float f) {
    unsigned int u = __builtin_bit_cast(unsigned int, f);
    u += 0x7FFFu + ((u >> 16) & 1u);
    return (ushort)(u >> 16);
}
// pack two floats' bf16 truncations into one dword with a single v_perm_b32
__device__ __forceinline__ int pk_trunc(float a, float b) {
    return (int)__builtin_amdgcn_perm(__builtin_bit_cast(unsigned, b),
                                      __builtin_bit_cast(unsigned, a),
                                      0x07060302u);
}
__device__ __forceinline__ float fast_exp2(float x) {
#if __has_builtin(__builtin_amdgcn_exp2f)
    return __builtin_amdgcn_exp2f(x);
#else
    return exp2f(x);
#endif
}

// ---------------------------------------------------------------------------
// Kernel 1: MFMA QKV projection (R6 version — best measured config).
// Wave tile = 64o x 32n; 2560 waves.  A-frags: fp32 W rows + v_perm pack.
// B-frags: 8 scalar fp32 x loads (stride N) + pack.  q pre-scaled by
// 1/sqrt(32)*log2(e).  Outputs bf16: qb,kb (B,N,32), vb (B,C,N).
// ---------------------------------------------------------------------------
__global__ __launch_bounds__(256) void qkv_mfma(
    const float* __restrict__ x,
    const float* __restrict__ Wq, const float* __restrict__ bq,
    const float* __restrict__ Wk, const float* __restrict__ bk,
    const float* __restrict__ Wv, const float* __restrict__ bv,
    ushort* __restrict__ qb, ushort* __restrict__ kb, ushort* __restrict__ vb)
{
    const int t = threadIdx.x;
    const int wave = t >> 6;
    const int lane = t & 63;
    const int l15 = lane & 15, qd = lane >> 4;
    const int b = blockIdx.z, m0 = blockIdx.y * 64;
    const int n0 = blockIdx.x * 128 + wave * 32;
    const float* xb = x + (size_t)b * CC * NN;
    const bool isqk = (m0 == 0);

    const float* wr[4];
    if (isqk) {
        wr[0] = Wq + (size_t)l15 * CC;
        wr[1] = Wq + (size_t)(16 + l15) * CC;
        wr[2] = Wk + (size_t)l15 * CC;
        wr[3] = Wk + (size_t)(16 + l15) * CC;
    } else {
        #pragma unroll
        for (int f = 0; f < 4; ++f) wr[f] = Wv + (size_t)(m0 - 64 + f * 16 + l15) * CC;
    }

    floatx4 z = {0.f, 0.f, 0.f, 0.f};
    floatx4 acc[4][2];
    #pragma unroll
    for (int i = 0; i < 4; ++i) { acc[i][0] = z; acc[i][1] = z; }

    for (int k0 = 0; k0 < CC; k0 += 32) {
        short8 af[4], bf[2];
        #pragma unroll
        for (int f = 0; f < 4; ++f) {
            const float* p = wr[f] + k0 + qd * 8;
            float w[8];
            #pragma unroll
            for (int j = 0; j < 8; ++j) w[j] = p[j];
            if (isqk && f < 2) {
                #pragma unroll
                for (int j = 0; j < 8; ++j) w[j] *= SCALEF;
            }
            intx4 d;
            d[0] = pk_trunc(w[0], w[1]); d[1] = pk_trunc(w[2], w[3]);
            d[2] = pk_trunc(w[4], w[5]); d[3] = pk_trunc(w[6], w[7]);
            af[f] = __builtin_bit_cast(short8, d);
        }
        #pragma unroll
        for (int f = 0; f < 2; ++f) {
            const float* p = xb + (size_t)(k0 + qd * 8) * NN + n0 + f * 16 + l15;
            float xv[8];
            #pragma unroll
            for (int j = 0; j < 8; ++j) xv[j] = p[(size_t)j * NN];
            intx4 d;
            d[0] = pk_trunc(xv[0], xv[1]); d[1] = pk_trunc(xv[2], xv[3]);
            d[2] = pk_trunc(xv[4], xv[5]); d[3] = pk_trunc(xv[6], xv[7]);
            bf[f] = __builtin_bit_cast(short8, d);
        }
        #pragma unroll
        for (int fm = 0; fm < 4; ++fm)
            #pragma unroll
            for (int fn = 0; fn < 2; ++fn)
                acc[fm][fn] = __builtin_amdgcn_mfma_f32_16x16x32_bf16(af[fm], bf[fn], acc[fm][fn], 0, 0, 0);
    }

    #pragma unroll
    for (int fm = 0; fm < 4; ++fm) {
        #pragma unroll
        for (int r = 0; r < 4; ++r) {
            int o = m0 + fm * 16 + qd * 4 + r;
            if (isqk) {
                if (fm < 2) {
                    float bo = bq[o] * SCALEF;
                    #pragma unroll
                    for (int fn = 0; fn < 2; ++fn)
                        qb[((size_t)b * NN + n0 + fn * 16 + l15) * DD + o] = f2bf(acc[fm][fn][r] + bo);
                } else {
                    float bo = bk[o - 32];
                    #pragma unroll
                    for (int fn = 0; fn < 2; ++fn)
                        kb[((size_t)b * NN + n0 + fn * 16 + l15) * DD + (o - 32)] = f2bf(acc[fm][fn][r] + bo);
                }
            } else {
                float bo = bv[o - 64];
                #pragma unroll
                for (int fn = 0; fn < 2; ++fn)
                    vb[((size_t)b * CC + (o - 64)) * NN + n0 + fn * 16 + l15] = f2bf(acc[fm][fn][r] + bo);
            }
        }
    }
}

// ---------------------------------------------------------------------------
// Kernel 2: MFMA flash attention (R6 structure, wider wave).  Block = 4
// waves = 4 key-quarters of one (64-q tile, 128-ch group); wave = 64q x
// 128ch over 1024 keys (32 tiles).  Halves R6's P-path redundancy (each
// P computed by 2 ch-group waves instead of 4) and halves wave count
// (2048 waves = 2/SIMD at ~230 VGPR).  No occupancy cap, no prefetch,
// per-f transient S processing.  Partial O/l additive; 3-barrier LDS tree.
// Grid (8,32,2): x = XCD slot, b = slot/2 pins each batch's K/V to 2 XCDs.
// ---------------------------------------------------------------------------
__global__ __launch_bounds__(256) void attn_mfma(
    const ushort* __restrict__ qb, const ushort* __restrict__ kb,
    const ushort* __restrict__ vb, ushort* __restrict__ aoT)
{
    __shared__ float red[2][8192];   // [slot][((f*8+ct)*4+r)*64 + lane] = 64 KB
    __shared__ float lredN[4][64];   // [wave][q]

    const int t = threadIdx.x;
    const int kh = t >> 6;               // key-quarter 0..3
    const int lane = t & 63;
    const int l15 = lane & 15;
    const int qd = lane >> 4;
    const int slot = blockIdx.x;         // ~XCD id (round-robin heuristic)
    const int b = slot >> 1;             // 2 XCDs per batch
    const int qt = (slot & 1) * 32 + blockIdx.y;
    const int q0 = qt * 64;
    const int c0 = blockIdx.z * 128;

    const ushort* krow = kb + ((size_t)b * NN + kh * 1024 + l15) * DD + qd * 8;
    const ushort* vrow[8];
    #pragma unroll
    for (int ct = 0; ct < 8; ++ct)
        vrow[ct] = vb + ((size_t)b * CC + c0 + ct * 16 + l15) * (size_t)NN + kh * 1024 + qd * 8;

    short8 qf[4];
    #pragma unroll
    for (int f = 0; f < 4; ++f)
        qf[f] = *(const short8*)(qb + ((size_t)b * NN + q0 + f * 16 + l15) * DD + qd * 8);

    const short8 ones = {0x3F80, 0x3F80, 0x3F80, 0x3F80, 0x3F80, 0x3F80, 0x3F80, 0x3F80};

    floatx4 z = {0.f, 0.f, 0.f, 0.f};
    floatx4 acc[4][8];   // [qfrag][chfrag]
    floatx4 accl[4];
    #pragma unroll
    for (int f = 0; f < 4; ++f) {
        accl[f] = z;
        #pragma unroll
        for (int c = 0; c < 8; ++c) acc[f][c] = z;
    }

    const int base  = (qd & 1) * 32 + l15;   // proven transpose lane mapping
    const int base2 = base + 16;
    const bool hi = (lane >= 32);

    for (int kt = 0; kt < 32; ++kt) {
        short8 kf0 = *(const short8*)(krow);
        short8 kf1 = *(const short8*)(krow + 16 * DD);
        short8 vf[8];
        #pragma unroll
        for (int ct = 0; ct < 8; ++ct)
            vf[ct] = *(const short8*)(vrow[ct]);
        krow += 32 * DD;
        #pragma unroll
        for (int ct = 0; ct < 8; ++ct) vrow[ct] += 32;

        #pragma unroll
        for (int f = 0; f < 4; ++f) {
            floatx4 s0 = __builtin_amdgcn_mfma_f32_16x16x32_bf16(kf0, qf[f], z, 0, 0, 0);
            floatx4 s1 = __builtin_amdgcn_mfma_f32_16x16x32_bf16(kf1, qf[f], z, 0, 0, 0);

            float e00 = fast_exp2(s0[0]), e01 = fast_exp2(s0[1]);
            float e02 = fast_exp2(s0[2]), e03 = fast_exp2(s0[3]);
            float e10 = fast_exp2(s1[0]), e11 = fast_exp2(s1[1]);
            float e12 = fast_exp2(s1[2]), e13 = fast_exp2(s1[3]);

            int A0 = pk_trunc(e00, e01);
            int A1 = pk_trunc(e02, e03);
            int B0 = pk_trunc(e10, e11);
            int B1 = pk_trunc(e12, e13);

            int w0a = __shfl(A0, base);  int w0b = __shfl(B0, base);
            int w1a = __shfl(A1, base);  int w1b = __shfl(B1, base);
            int w2a = __shfl(A0, base2); int w2b = __shfl(B0, base2);
            int w3a = __shfl(A1, base2); int w3b = __shfl(B1, base2);

            intx4 ptd;
            ptd[0] = hi ? w0b : w0a;
            ptd[1] = hi ? w1b : w1a;
            ptd[2] = hi ? w2b : w2a;
            ptd[3] = hi ? w3b : w3a;
            short8 pt = __builtin_bit_cast(short8, ptd);

            accl[f] = __builtin_amdgcn_mfma_f32_16x16x32_bf16(ones, pt, accl[f], 0, 0, 0);

            #pragma unroll
            for (int ct = 0; ct < 8; ++ct)
                acc[f][ct] = __builtin_amdgcn_mfma_f32_16x16x32_bf16(vf[ct], pt, acc[f][ct], 0, 0, 0);
        }
    }

    float lsum[4];
    #pragma unroll
    for (int f = 0; f < 4; ++f) lsum[f] = accl[f][0];

    // publish l partials (all waves, separate buffer — no conflict with tree)
    if (qd == 0)
        #pragma unroll
        for (int f = 0; f < 4; ++f) lredN[kh][f * 16 + l15] = lsum[f];

    // ---- O reduction tree over key-quarters: (0+=1, 2+=3), then 0+=2 ----
    if (kh & 1) {
        const int s = kh >> 1;
        #pragma unroll
        for (int f = 0; f < 4; ++f)
            #pragma unroll
            for (int ct = 0; ct < 8; ++ct)
                #pragma unroll
                for (int r = 0; r < 4; ++r)
                    red[s][((f * 8 + ct) * 4 + r) * 64 + lane] = acc[f][ct][r];
    }
    __syncthreads();
    if (!(kh & 1)) {
        const int s = kh >> 1;
        #pragma unroll
        for (int f = 0; f < 4; ++f)
            #pragma unroll
            for (int ct = 0; ct < 8; ++ct)
                #pragma unroll
                for (int r = 0; r < 4; ++r)
                    acc[f][ct][r] += red[s][((f * 8 + ct) * 4 + r) * 64 + lane];
    }
    __syncthreads();
    if (kh == 2) {
        #pragma unroll
        for (int f = 0; f < 4; ++f)
            #pragma unroll
            for (int ct = 0; ct < 8; ++ct)
                #pragma unroll
                for (int r = 0; r < 4; ++r)
                    red[0][((f * 8 + ct) * 4 + r) * 64 + lane] = acc[f][ct][r];
    }
    __syncthreads();
    if (kh == 0) {
        #pragma unroll
        for (int f = 0; f < 4; ++f) {
            #pragma unroll
            for (int ct = 0; ct < 8; ++ct)
                #pragma unroll
                for (int r = 0; r < 4; ++r)
                    acc[f][ct][r] += red[0][((f * 8 + ct) * 4 + r) * 64 + lane];
        }
        #pragma unroll
        for (int f = 0; f < 4; ++f) {
            const float l = lredN[0][f * 16 + l15] + lredN[1][f * 16 + l15]
                          + lredN[2][f * 16 + l15] + lredN[3][f * 16 + l15];
            const float inv = 1.0f / l;
            ushort* dst = aoT + ((size_t)b * NN + q0 + f * 16 + l15) * CC + c0 + qd * 4;
            #pragma unroll
            for (int ct = 0; ct < 8; ++ct) {
                ushort4 h;
                h.x = f2bf(acc[f][ct][0] * inv);
                h.y = f2bf(acc[f][ct][1] * inv);
                h.z = f2bf(acc[f][ct][2] * inv);
                h.w = f2bf(acc[f][ct][3] * inv);
                *(ushort4*)(dst + ct * 16) = h;
            }
        }
    }
}

// ---------------------------------------------------------------------------
// Kernel 3: MFMA output projection + residual.  Wave tile = 64m x 32n ->
// 512 blocks (2/CU).  A-frags cast from fp32 Wp in-register (contiguous ->
// compiler merges to dwordx4); B-frags straight short8 loads from bf16 aoT.
// out = x + gamma*(Wp@ao + bp).
// ---------------------------------------------------------------------------
__global__ __launch_bounds__(256) void proj_mfma(
    const ushort* __restrict__ aoT, const float* __restrict__ Wp,
    const float* __restrict__ bp, const float* __restrict__ x,
    const float* __restrict__ gamma, float* __restrict__ out)
{
    const int t = threadIdx.x;
    const int wave = t >> 6;
    const int lane = t & 63;
    const int l15 = lane & 15;
    const int qd = lane >> 4;
    const int b = blockIdx.z;
    const int m0 = blockIdx.y * 64;
    const int n0 = blockIdx.x * 128 + wave * 32;

    floatx4 z = {0.f, 0.f, 0.f, 0.f};
    floatx4 acc[4][2];   // [fm][fn]
    #pragma unroll
    for (int i = 0; i < 4; ++i) { acc[i][0] = z; acc[i][1] = z; }

    const ushort* arow = aoT + ((size_t)b * NN + n0 + l15) * CC + qd * 8;
    const float* wrow = Wp + (size_t)(m0 + l15) * CC + qd * 8;

    #pragma unroll
    for (int k0 = 0; k0 < CC; k0 += 32) {
        short8 af[4], bf[2];
        #pragma unroll
        for (int f = 0; f < 4; ++f) {
            const float* p = wrow + (size_t)f * 16 * CC + k0;
            intx4 d;
            d[0] = pk_trunc(p[0], p[1]); d[1] = pk_trunc(p[2], p[3]);
            d[2] = pk_trunc(p[4], p[5]); d[3] = pk_trunc(p[6], p[7]);
            af[f] = __builtin_bit_cast(short8, d);
        }
        #pragma unroll
        for (int f = 0; f < 2; ++f)
            bf[f] = *(const short8*)(arow + (size_t)f * 16 * CC + k0);
        #pragma unroll
        for (int fm = 0; fm < 4; ++fm)
            #pragma unroll
            for (int fn = 0; fn < 2; ++fn)
                acc[fm][fn] = __builtin_amdgcn_mfma_f32_16x16x32_bf16(af[fm], bf[fn], acc[fm][fn], 0, 0, 0);
    }

    const float g = gamma[0];
    #pragma unroll
    for (int fm = 0; fm < 4; ++fm) {
        #pragma unroll
        for (int r = 0; r < 4; ++r) {
            int m = m0 + fm * 16 + qd * 4 + r;
            float bpv = bp[m];
            #pragma unroll
            for (int fn = 0; fn < 2; ++fn) {
                size_t addr = ((size_t)b * CC + m) * NN + n0 + fn * 16 + l15;
                out[addr] = fmaf(g, acc[fm][fn][r] + bpv, x[addr]);
            }
        }
    }
}

extern "C" void kernel_launch(void* const* d_in, const int* in_sizes, int n_in,
                              void* d_out, int out_size, void* d_ws, size_t ws_size,
                              hipStream_t stream)
{
    const float* x     = (const float*)d_in[0];
    const float* Wq    = (const float*)d_in[1];
    const float* bq    = (const float*)d_in[2];
    const float* Wk    = (const float*)d_in[3];
    const float* bk    = (const float*)d_in[4];
    const float* Wv    = (const float*)d_in[5];
    const float* bv    = (const float*)d_in[6];
    const float* Wp    = (const float*)d_in[7];
    const float* bp    = (const float*)d_in[8];
    const float* gamma = (const float*)d_in[9];
    float* out = (float*)d_out;

    ushort* qbw = (ushort*)d_ws;                        // B*N*32  bf16 = 1 MB
    ushort* kbw = qbw + (size_t)BB * NN * DD;           // B*N*32  bf16 = 1 MB
    ushort* vbw = kbw + (size_t)BB * NN * DD;           // B*C*N   bf16 = 8 MB
    ushort* aoT = vbw + (size_t)BB * CC * NN;           // B*N*C   bf16 = 8 MB

    qkv_mfma<<<dim3(NN / 128, 5, BB), 256, 0, stream>>>(x, Wq, bq, Wk, bk, Wv, bv, qbw, kbw, vbw);
    attn_mfma<<<dim3(8, 32, 2), 256, 0, stream>>>(qbw, kbw, vbw, aoT);
    proj_mfma<<<dim3(NN / 128, CC / 64, BB), 256, 0, stream>>>(aoT, Wp, bp, x, gamma, out);
}